// Round 1
// baseline (774.930 us; speedup 1.0000x reference)
//
#include <hip/hip_runtime.h>
#include <math.h>

#define T_STEPS 512
#define N_BATCH 32
#define C_CLS   8000
#define S_TGT   40

// ln(2^-126) = ln(np.finfo(np.float32).tiny)
#define LOG_TINY (-87.3365447505531f)

__device__ __forceinline__ float log_add(float a, float b) {
    float x = fmaxf(a, b);
    float y = fminf(a, b);
    // ln(1 + e^(y-x)); y-x <= 0 so e^d in (0,1]. Fast exp/log: ~1e-6 abs err,
    // negligible vs. the 8.5 absmax threshold over 512 accumulation steps.
    return x + __logf(1.0f + __expf(y - x));
}

extern "C" __global__ __launch_bounds__(64)
void ctc_fwd(const float* __restrict__ lp,      // (T, N, C)
             const int*   __restrict__ targets, // (N, S)
             const int*   __restrict__ in_len,  // ignored by reference
             const int*   __restrict__ tgt_len, // (N,)
             float*       __restrict__ out) {   // (N,)
    const int n = blockIdx.x;   // batch item
    const int l = threadIdx.x;  // lane: owns slots 2l (blank) and 2l+1 (target l)

    // Per-lane static state ------------------------------------------------
    int cls = 0;
    if (l < S_TGT) cls = targets[n * S_TGT + l];
    int prev_cls = __shfl_up(cls, 1);
    const bool skip = (l >= 1 && l < S_TGT) && (cls != prev_cls);

    // alpha(t=0): slot0 = lp[0,n,blank], slot1 = lp[0,n,tgt0], rest LOG_TINY
    const float* row0 = lp + (size_t)n * C_CLS;
    float a_e, a_o;
    if (l == 0) { a_e = row0[0]; a_o = row0[cls]; }
    else        { a_e = LOG_TINY; a_o = LOG_TINY; }

    // Software-pipelined gather: depth 7 (511 steps = 7 * 73 exactly) ------
    const size_t rstride = (size_t)N_BATCH * C_CLS;
    constexpr int P = 7;
    float pb[P], pt[P];
#pragma unroll
    for (int i = 0; i < P; ++i) {
        const float* row = lp + (size_t)(1 + i) * rstride + (size_t)n * C_CLS;
        pb[i] = row[0];    // blank prob (wave-uniform address -> 1 line)
        pt[i] = row[cls];  // per-lane target prob (scattered in 32KB row)
    }

    int t = 1;
    for (int outer = 0; outer < (T_STEPS - 1) / P; ++outer) {
#pragma unroll
        for (int i = 0; i < P; ++i) {
            // Consume this step's probs FIRST (loaded 7 steps ago, vmcnt done),
            // then issue the t+7 load straight into pb[i]/pt[i] so the waitcnt
            // lands 7 iterations from now.
            float lpb = pb[i], lpt = pt[i];
            int tn = t + P; if (tn > T_STEPS - 1) tn = T_STEPS - 1; // tail clamp; values unused
            const float* rown = lp + (size_t)tn * rstride + (size_t)n * C_CLS;
            pb[i] = rown[0];
            pt[i] = rown[cls];

            // alpha update (old values on RHS)
            float up_o = __shfl_up(a_o, 1);                   // alpha[2l-1]
            float ne = (l == 0) ? a_e : log_add(a_e, up_o);   // blank slot: never skips
            float bo = log_add(a_o, a_e);
            bo = skip ? log_add(bo, up_o) : bo;               // cndmask, no divergence
            a_e = ne + lpb;
            a_o = bo + lpt;
            ++t;
        }
    }

    // loss = -logadd(alpha[2TL], alpha[2TL-1]) / TL
    const int TL = tgt_len[n];          // in [10, 40]
    float v1 = __shfl(a_e, TL);         // slot 2TL   (even, lane TL)
    float v2 = __shfl(a_o, TL - 1);     // slot 2TL-1 (odd,  lane TL-1)
    if (l == 0) {
        float loss = log_add(v1, v2);
        out[n] = -loss / (float)TL;
    }
    (void)in_len; // reference ignores input_lengths
}

extern "C" void kernel_launch(void* const* d_in, const int* in_sizes, int n_in,
                              void* d_out, int out_size, void* d_ws, size_t ws_size,
                              hipStream_t stream) {
    const float* lp  = (const float*)d_in[0];
    const int*   tg  = (const int*)d_in[1];
    const int*   il  = (const int*)d_in[2];
    const int*   tl  = (const int*)d_in[3];
    float*       out = (float*)d_out;
    hipLaunchKernelGGL(ctc_fwd, dim3(N_BATCH), dim3(64), 0, stream,
                       lp, tg, il, tl, out);
}

// Round 2
// 651.478 us; speedup vs baseline: 1.1895x; 1.1895x over previous
//
#include <hip/hip_runtime.h>
#include <math.h>

#define T_STEPS 512
#define N_BATCH 32
#define C_CLS   8000
#define S_TGT   40
#define ROW     48              // padded row: slots 0..39 = targets, 40 = blank
#define LOG_TINY (-87.3365447505531f)   // ln(np.finfo(np.float32).tiny)
#define NEG_BIG  (-1.0e30f)             // "-inf" sentinel: finite, exp() -> 0, no NaN

// ---------------------------------------------------------------------------
// Kernel A: massively parallel gather. lp is (T, N, C); we only ever need
// lp[t, n, targets[n, l]] and lp[t, n, 0]. 16384 blocks x 64 threads gives
// ~670K in-flight scattered loads -> HBM latency fully hidden (R1 kernel had
// only ~450 in flight -> 75 GB/s effective -> 570us; that was the bottleneck).
// Packed layout (n, t, ROW) so kernel B reads contiguous per batch.
// ---------------------------------------------------------------------------
extern "C" __global__ __launch_bounds__(64)
void ctc_gather(const float* __restrict__ lp,
                const int*   __restrict__ targets,
                float*       __restrict__ packed) {
    const int t = blockIdx.x;
    const int n = blockIdx.y;
    const int l = threadIdx.x;
    if (l > 40) return;
    const int cls = (l < S_TGT) ? targets[n * S_TGT + l] : 0;   // slot 40 = blank
    const float v = lp[((size_t)t * N_BATCH + n) * C_CLS + cls];
    packed[((size_t)n * T_STEPS + t) * ROW + l] = v;
}

// ---------------------------------------------------------------------------
// Kernel B: the sequential alpha recurrence. One wave per batch item.
// Lane l owns slots 2l (blank) and 2l+1 (target l). Only cross-lane traffic
// is shfl_up(a_o, 1). Per step: one coalesced dword load from the packed
// array (L2-resident), blank prob broadcast via shfl(v, 40).
// ---------------------------------------------------------------------------
extern "C" __global__ __launch_bounds__(64)
void ctc_rec(const float* __restrict__ packed,
             const int*   __restrict__ targets,
             const int*   __restrict__ tgt_len,
             float*       __restrict__ out) {
    const int n = blockIdx.x;
    const int l = threadIdx.x;

    const int cls      = (l < S_TGT) ? targets[n * S_TGT + l] : 0;
    const int prev_cls = __shfl_up(cls, 1);
    const bool skip    = (l >= 1 && l < S_TGT) && (cls != prev_cls);

    const float* base = packed + (size_t)n * T_STEPS * ROW;
    const int ll = (l <= 40) ? l : 40;   // lanes 41..63: harmless defined load

    // t = 0 init: slot0 = blank prob, slot1 = target0 prob, rest LOG_TINY
    float a_e, a_o;
    {
        const float v0 = base[ll];
        const float b0 = __shfl(v0, 40);
        a_e = (l == 0) ? b0 : LOG_TINY;
        a_o = (l == 0) ? v0 : LOG_TINY;
    }

    // Register pipeline, depth 7 (511 = 7 * 73 exactly)
    constexpr int P = 7;
    float pv[P];
#pragma unroll
    for (int i = 0; i < P; ++i) pv[i] = base[(1 + i) * ROW + ll];

    int t = 1;
    for (int outer = 0; outer < (T_STEPS - 1) / P; ++outer) {
#pragma unroll
        for (int i = 0; i < P; ++i) {
            const float v = pv[i];                      // loaded P steps ago
            int tn = t + P; if (tn > T_STEPS - 1) tn = T_STEPS - 1;
            pv[i] = base[tn * ROW + ll];                // waitcnt lands P iters out

            const float lpb  = __shfl(v, 40);           // blank prob broadcast
            const float up_o = __shfl_up(a_o, 1);       // alpha[2l-1]

            // even slot: new = logadd(a_e, up_o) + lpb   (lane0: just a_e + lpb)
            const float ue = (l == 0) ? NEG_BIG : up_o;
            const float m2 = fmaxf(a_e, ue);
            const float ne = m2 + __logf(__expf(a_e - m2) + __expf(ue - m2)) + lpb;

            // odd slot: new = logadd3(a_o, a_e, skip ? up_o : -inf) + lpt
            const float c  = skip ? up_o : NEG_BIG;
            const float m3 = fmaxf(fmaxf(a_o, a_e), c);
            const float no = m3 + __logf(__expf(a_o - m3) + __expf(a_e - m3)
                                         + __expf(c - m3)) + v;
            a_e = ne;
            a_o = no;
            ++t;
        }
    }

    // loss = -logadd(alpha[2TL], alpha[2TL-1]) / TL
    const int TL = tgt_len[n];              // in [10, 40]
    const float v1 = __shfl(a_e, TL);       // slot 2TL   (even, lane TL)
    const float v2 = __shfl(a_o, TL - 1);   // slot 2TL-1 (odd,  lane TL-1)
    if (l == 0) {
        const float x = fmaxf(v1, v2), y = fminf(v1, v2);
        const float loss = x + __logf(1.0f + __expf(y - x));
        out[n] = -loss / (float)TL;
    }
}

extern "C" void kernel_launch(void* const* d_in, const int* in_sizes, int n_in,
                              void* d_out, int out_size, void* d_ws, size_t ws_size,
                              hipStream_t stream) {
    const float* lp  = (const float*)d_in[0];
    const int*   tg  = (const int*)d_in[1];
    const int*   tl  = (const int*)d_in[3];
    float*       out = (float*)d_out;
    float*       packed = (float*)d_ws;     // needs 32*512*48*4 = 3.1 MB

    hipLaunchKernelGGL(ctc_gather, dim3(T_STEPS, N_BATCH), dim3(64), 0, stream,
                       lp, tg, packed);
    hipLaunchKernelGGL(ctc_rec, dim3(N_BATCH), dim3(64), 0, stream,
                       packed, tg, tl, out);
}